// Round 5
// baseline (14207.628 us; speedup 1.0000x reference)
//
#include <hip/hip_runtime.h>

typedef unsigned short u16;
typedef unsigned int   u32;

static __device__ __forceinline__ float sigf (float x){ return 1.0f/(1.0f+__expf(-x)); }
static __device__ __forceinline__ float tanh_(float x){ return 2.0f/(1.0f+__expf(-2.0f*x)) - 1.0f; }

// sizes
#define NM 2730            // 273*10 distinct (t, j=b%10) rows
#define N_O0 878080        // 245*128*28
#define N_O3 978432        // 273*128*28

// ---- transpose f32 -> f32: dst[c*rows+r] = src[r*cols+c] ----
__global__ void k_trf(const float* __restrict__ src, float* __restrict__ dst, int rows, int cols){
  int i = blockIdx.x*256 + threadIdx.x;
  if(i >= rows*cols) return;
  int c = i / rows, r = i - c*rows;
  dst[i] = src[r*cols + c];
}

// ---- x (128,300) f32 -> xT[t*128+b] f32 ----
__global__ void k_xT(const float* __restrict__ x, float* __restrict__ xT){
  int i = blockIdx.x*256 + threadIdx.x;
  if(i >= 300*128) return;
  int t = i >> 7, b = i & 127;
  xT[i] = x[b*300 + t];
}

// ---- exponential-smoothing scan: 128 threads, one per batch row ----
__global__ void k_es(const float* __restrict__ xT, const float* __restrict__ alpha,
                     const float* __restrict__ gamma, const float* __restrict__ iseas,
                     float* __restrict__ ST, float* __restrict__ lvlT){
  int b = threadIdx.x;
  float a = sigf(alpha[b]);
  float g = sigf(gamma[b]);
  float S0[7];
  #pragma unroll
  for(int i=0;i<7;i++){ S0[i] = __expf(iseas[b*7+i]); ST[i*128+b] = S0[i]; }
  ST[7*128+b] = S0[0];
  float q0=S0[1],q1=S0[2],q2=S0[3],q3=S0[4],q4=S0[5],q5=S0[6],q6=S0[0];
  float lvl = xT[b]/S0[0];
  lvlT[b] = lvl;
  for(int t=1;t<300;t++){
    float xt = xT[t*128+b];
    float s  = q0;
    lvl = a*(xt/s) + (1.0f-a)*lvl;
    float sn = g*(xt/lvl) + (1.0f-g)*s;
    q0=q1;q1=q2;q2=q3;q3=q4;q4=q5;q5=q6;q6=sn;
    lvlT[t*128+b]   = lvl;
    ST[(t+7)*128+b] = sn;
  }
}

// ---- build window_input for the 10 distinct rows: win[(t*10+j)*49 + f] ----
__global__ void k_win(const float* __restrict__ xT, const float* __restrict__ ST,
                      const float* __restrict__ lvlT, const float* __restrict__ cats,
                      const float* __restrict__ mp, float* __restrict__ win){
  int i = blockIdx.x*256 + threadIdx.x;
  if(i >= NM*49) return;
  int f = i % 49;
  int m = i / 49;
  int j = m % 10, t = m / 10;
  float v;
  if(f < 28){
    int c = t + f;
    v = xT[c*128 + j] / ST[c*128 + j] / lvlT[(t+27)*128 + j];
  } else if(f < 48){
    v = cats[j*20 + (f-28)];
  } else {
    v = mp[0];
  }
  win[i] = v;
}

// ---- actual_values (window_output), per real batch row b (f32 out) ----
__global__ void k_wout(const float* __restrict__ xT, const float* __restrict__ ST,
                       const float* __restrict__ lvlT, float* __restrict__ out1){
  int i = blockIdx.x*256 + threadIdx.x;
  if(i >= N_O0) return;
  int o = i % 28;
  int b = (i/28) % 128;
  int t = i/(28*128);
  int c = 28 + t + o;                    // L + t + o  (<= 299)
  out1[i] = xT[c*128+b] / ST[c*128+b] / lvlT[(27+t)*128+b];
}

// ---- batched xz = X @ WihT + b : block = 8 rows x 1024 gates, 256 threads ----
__global__ __launch_bounds__(256) void k_gemm(const float* __restrict__ X,
                                              const float* __restrict__ WT,   // [F][1024] f32
                                              const float* __restrict__ bias, // [1024] f32
                                              float* __restrict__ Z, int F){
  __shared__ float Xs[8][256];
  const int tid = threadIdx.x;
  const int m0 = blockIdx.x*8;
  for(int p=0;p<8;p++){
    int m = m0+p;
    for(int f=tid; f<F; f+=256)
      Xs[p][f] = (m < NM) ? X[m*F+f] : 0.0f;
  }
  __syncthreads();
  float acc0[8], acc1[8], acc2[8], acc3[8];
  {
    float b0 = bias[tid];
    float b1 = bias[tid+256];
    float b2 = bias[tid+512];
    float b3 = bias[tid+768];
    #pragma unroll
    for(int p=0;p<8;p++){ acc0[p]=b0; acc1[p]=b1; acc2[p]=b2; acc3[p]=b3; }
  }
  #pragma unroll 4
  for(int f=0; f<F; f++){
    float w0 = WT[f*1024 + tid      ];
    float w1 = WT[f*1024 + tid+256  ];
    float w2 = WT[f*1024 + tid+512  ];
    float w3 = WT[f*1024 + tid+768  ];
    #pragma unroll
    for(int p=0;p<8;p++){
      float xv = Xs[p][f];
      acc0[p] += w0*xv; acc1[p] += w1*xv; acc2[p] += w2*xv; acc3[p] += w3*xv;
    }
  }
  for(int p=0;p<8;p++){
    int m = m0+p;
    if(m < NM){
      float* zb = Z + m*1024 + tid;
      zb[0]=acc0[p]; zb[256]=acc1[p]; zb[512]=acc2[p]; zb[768]=acc3[p];
    }
  }
}

// ---- LSTM scan v3: one WG (1024 thr) per chain, Whh register-resident ----
// Thread tid owns gate-row tid (Whh row order: i 0..255, f 256.., g 512..,
// o 768..) and holds its 256 f32 weights in VGPRs, loaded once (coalesced
// from WhhT[k][row]). Per step: broadcast ds_read of h from LDS, 256 FMAs,
// zLDS exchange, 256-thread gate combine. Intra-WG syncs only.
__global__ __launch_bounds__(1024) void k_scan3(
    const float* __restrict__ Z,
    const float* __restrict__ WT,    // [256][1024] f32 (WhhT: [k][row])
    float* __restrict__ Y,
    const float* __restrict__ RES,
    int d)
{
  __shared__ float hLDS[256];
  __shared__ float zLDS[1024];
  const int tid   = threadIdx.x;
  const int chain = blockIdx.x;
  const int j = chain % 10;
  const int r = chain / 10;
  const int ns = (273 - r + d - 1)/d;

  // one-time coalesced weight load: wv[k] = WhhT[k][tid]
  float wv[256];
  #pragma unroll
  for(int k=0;k<256;k++) wv[k] = WT[k*1024 + tid];

  float cc = 0.0f;                 // c-state (threads 0..255)
  if(tid < 256) hLDS[tid] = 0.0f;
  __syncthreads();

  int t = r;
  for(int s=0; s<ns; s++, t+=d){
    const size_t row = (size_t)(t*10 + j);
    float zv = Z[row*1024 + tid];  // prefetch (hidden behind the dot)
    float a0=0.f, a1=0.f, a2=0.f, a3=0.f;
    const float4* hp = (const float4*)hLDS;
    #pragma unroll
    for(int i=0;i<64;i++){
      float4 h4 = hp[i];           // broadcast: all lanes same address
      a0 += wv[4*i  ]*h4.x;
      a1 += wv[4*i+1]*h4.y;
      a2 += wv[4*i+2]*h4.z;
      a3 += wv[4*i+3]*h4.w;
    }
    zLDS[tid] = (a0+a1) + (a2+a3) + zv;
    __syncthreads();
    if(tid < 256){
      float zi = zLDS[tid      ];
      float zf = zLDS[tid + 256];
      float zg = zLDS[tid + 512];
      float zo = zLDS[tid + 768];
      cc = sigf(zf)*cc + sigf(zi)*tanh_(zg);
      float h = sigf(zo)*tanh_(cc);
      hLDS[tid] = h;
      float o = h;
      if(RES) o += RES[row*256 + tid];
      Y[row*256 + tid] = o;
    }
    __syncthreads();
  }
}

// ---- head: h = tanh(y4 @ linW.T + lb); rnn = h @ scW.T + sb ----
__global__ __launch_bounds__(256) void k_head(const float* __restrict__ Y4,
    const float* __restrict__ LWT,  // [256][256] f32 (linWT: [f][u])
    const float* __restrict__ lb,
    const float* __restrict__ SWT,  // [256][28] f32  (scoreT: [f][o])
    const float* __restrict__ sb,
    float* __restrict__ R){
  __shared__ float v [8][256];
  __shared__ float h2[8][256];
  const int tid = threadIdx.x;
  const int m0 = blockIdx.x*8;
  for(int p=0;p<8;p++){
    int m = m0+p;
    v[p][tid] = (m<NM) ? Y4[m*256+tid] : 0.0f;
  }
  __syncthreads();
  float acc[8];
  float bz = lb[tid];
  #pragma unroll
  for(int p=0;p<8;p++) acc[p]=bz;
  #pragma unroll 4
  for(int f=0; f<256; f++){
    float w = LWT[f*256+tid];
    #pragma unroll
    for(int p=0;p<8;p++) acc[p] += w * v[p][f];
  }
  #pragma unroll
  for(int p=0;p<8;p++) h2[p][tid] = tanh_(acc[p]);
  __syncthreads();
  if(tid < 224){
    int o = tid % 28, p = tid / 28;
    int m = m0 + p;
    if(m < NM){
      float a = sb[o];
      for(int f=0; f<256; f++) a += SWT[f*28+o] * h2[p][f];
      R[m*28+o] = a;
    }
  }
}

// ---- final outputs (f32) ----
// S_ext = concat(S_full[0:307], S_full[300:307]); S_ext[-28:][o] =
//   S_full[286+o] (o<21) else S_full[279+o]
__global__ void k_out(const float* __restrict__ R, const float* __restrict__ ST,
                      const float* __restrict__ lvlT, const float* __restrict__ val,
                      float* __restrict__ out){
  int i = blockIdx.x*256 + threadIdx.x;
  float* o0 = out;                 // prediction_values (245,128,28)
  float* o2 = out + 1756160;       // holdout_prediction (128,28)
  float* o3 = out + 1759744;       // rnn_out (273,128,28)
  float* o4 = out + 2738176;       // hav (128,28)
  float* o5 = out + 2741760;       // hav_norm (128,28)
  if(i < N_O3){
    int o = i % 28;
    int b = (i/28) % 128;
    int t = i/(28*128);
    float vv = R[(t*10 + (b%10))*28 + o];
    o3[i] = vv;
    if(i < N_O0) o0[i] = vv;       // rnn_out[:-OUT], same linear layout
  }
  if(i < 128*28){
    int b = i/28, o = i%28;
    int col = (o < 21) ? (286+o) : (279+o);
    float Sm = ST[col*128 + b];
    float lv = lvlT[299*128 + b];
    float hv = R[(2720 + (b%10))*28 + o] * Sm * lv;
    o2[i] = (hv > 0.0f) ? hv : 0.0f;
    o4[i] = val[i];
    o5[i] = val[i] / Sm / lv;
  }
}

extern "C" void kernel_launch(void* const* d_in, const int* in_sizes, int n_in,
                              void* d_out, int out_size, void* d_ws, size_t ws_size,
                              hipStream_t stream){
  (void)in_sizes; (void)n_in; (void)out_size; (void)ws_size;
  const float* x     = (const float*)d_in[0];
  const float* val   = (const float*)d_in[1];
  const float* alpha = (const float*)d_in[2];
  const float* gamma = (const float*)d_in[3];
  const float* iseas = (const float*)d_in[4];
  const float* cats  = (const float*)d_in[5];
  const float* mp    = (const float*)d_in[6];
  const float* Wih[4]  = {(const float*)d_in[7],  (const float*)d_in[10], (const float*)d_in[13], (const float*)d_in[16]};
  const float* Whh[4]  = {(const float*)d_in[8],  (const float*)d_in[11], (const float*)d_in[14], (const float*)d_in[17]};
  const float* bias[4] = {(const float*)d_in[9],  (const float*)d_in[12], (const float*)d_in[15], (const float*)d_in[18]};
  const float* linW  = (const float*)d_in[19];
  const float* linb  = (const float*)d_in[20];
  const float* scW   = (const float*)d_in[21];
  const float* scb   = (const float*)d_in[22];

  // ---- workspace layout (all f32) ----
  float* Fw   = (float*)d_ws;
  float* ST   = Fw;                 // 39296
  float* lvlT = ST   + 39296;       // 38400
  float* xT   = lvlT + 38400;       // 38400
  float* win  = xT   + 38400;       // 133776
  float* xz   = win  + 133776;      // 2795520
  float* yA   = xz   + 2795520;     // 698880  (L1 out / L3 out / L4 out)
  float* yB   = yA   + 698880;      // 698880  (L2 out, residual)
  float* rnn  = yB   + 698880;      // 76448
  float* WB   = rnn  + 76448;
  float* whhT[4], *wihT[4];
  for(int l=0;l<4;l++) whhT[l] = WB + (size_t)l*262144;          // 4 * 256*1024
  wihT[0] = WB + (size_t)4*262144;                               // 50176
  wihT[1] = wihT[0] + 50176;
  wihT[2] = wihT[1] + 262144;
  wihT[3] = wihT[2] + 262144;
  float* linWT = wihT[3] + 262144;  // 65536
  float* scT   = linWT + 65536;     // 7168

  // ---- weight prep (f32 transposes) ----
  for(int l=0;l<4;l++)
    k_trf<<<(262144+255)/256, 256, 0, stream>>>(Whh[l], whhT[l], 1024, 256);
  k_trf<<<(1024*49+255)/256, 256, 0, stream>>>(Wih[0], wihT[0], 1024, 49);
  for(int l=1;l<4;l++)
    k_trf<<<(262144+255)/256, 256, 0, stream>>>(Wih[l], wihT[l], 1024, 256);
  k_trf<<<(65536+255)/256, 256, 0, stream>>>(linW, linWT, 256, 256);
  k_trf<<<(7168+255)/256, 256, 0, stream>>>(scW, scT, 28, 256);

  // ---- ES scan + windows ----
  k_xT<<<150, 256, 0, stream>>>(x, xT);
  k_es<<<1, 128, 0, stream>>>(xT, alpha, gamma, iseas, ST, lvlT);
  k_win<<<(NM*49+255)/256, 256, 0, stream>>>(xT, ST, lvlT, cats, mp, win);
  k_wout<<<N_O0/256, 256, 0, stream>>>(xT, ST, lvlT, (float*)d_out + 878080);

  // ---- 4 LSTM layers: batched Wih GEMM + single-CU register scan ----
  const int    dlt[4]    = {1, 2, 2, 6};
  const int    chains[4] = {10, 20, 20, 60};
  const float* Xin[4]    = {win, yA, yB, yA};
  float*       Yout[4]   = {yA, yB, yA, yA};
  const int    Fdim[4]   = {49, 256, 256, 256};
  for(int l=0;l<4;l++){
    k_gemm<<<(NM+7)/8, 256, 0, stream>>>(Xin[l], wihT[l], bias[l], xz, Fdim[l]);
    k_scan3<<<chains[l], 1024, 0, stream>>>(xz, whhT[l], Yout[l],
                                            (l==3) ? yB : (const float*)nullptr, dlt[l]);
  }

  // ---- head + outputs ----
  k_head<<<(NM+7)/8, 256, 0, stream>>>(yA, linWT, linb, scT, scb, rnn);
  k_out<<<N_O3/256, 256, 0, stream>>>(rnn, ST, lvlT, val, (float*)d_out);
}

// Round 6
// 3054.645 us; speedup vs baseline: 4.6512x; 4.6512x over previous
//
#include <hip/hip_runtime.h>

typedef unsigned short u16;
typedef unsigned int   u32;

static __device__ __forceinline__ u16 f2bf(float f){
  u32 u = __float_as_uint(f);
  u32 r = u + 0x7fffu + ((u>>16)&1u);   // RNE
  return (u16)(r>>16);
}
static __device__ __forceinline__ float sigf (float x){ return 1.0f/(1.0f+__expf(-x)); }
static __device__ __forceinline__ float tanh_(float x){ return 2.0f/(1.0f+__expf(-2.0f*x)) - 1.0f; }

// sizes
#define NM 2730            // 273*10 distinct (t, j=b%10) rows
#define N_O0 878080        // 245*128*28
#define N_O3 978432        // 273*128*28

// ---- transpose f32 -> f32: dst[c*rows+r] = src[r*cols+c] ----
__global__ void k_trf(const float* __restrict__ src, float* __restrict__ dst, int rows, int cols){
  int i = blockIdx.x*256 + threadIdx.x;
  if(i >= rows*cols) return;
  int c = i / rows, r = i - c*rows;
  dst[i] = src[r*cols + c];
}

// ---- transpose f32 -> bf16: dst[c*rows+r] = bf16(src[r*cols+c]) ----
__global__ void k_trb(const float* __restrict__ src, u16* __restrict__ dst, int rows, int cols){
  int i = blockIdx.x*256 + threadIdx.x;
  if(i >= rows*cols) return;
  int c = i / rows, r = i - c*rows;
  dst[i] = f2bf(src[r*cols + c]);
}

// ---- x (128,300) f32 -> xT[t*128+b] f32 ----
__global__ void k_xT(const float* __restrict__ x, float* __restrict__ xT){
  int i = blockIdx.x*256 + threadIdx.x;
  if(i >= 300*128) return;
  int t = i >> 7, b = i & 127;
  xT[i] = x[b*300 + t];
}

// ---- exponential-smoothing scan: 128 threads, one per batch row ----
__global__ void k_es(const float* __restrict__ xT, const float* __restrict__ alpha,
                     const float* __restrict__ gamma, const float* __restrict__ iseas,
                     float* __restrict__ ST, float* __restrict__ lvlT){
  int b = threadIdx.x;
  float a = sigf(alpha[b]);
  float g = sigf(gamma[b]);
  float S0[7];
  #pragma unroll
  for(int i=0;i<7;i++){ S0[i] = __expf(iseas[b*7+i]); ST[i*128+b] = S0[i]; }
  ST[7*128+b] = S0[0];
  float q0=S0[1],q1=S0[2],q2=S0[3],q3=S0[4],q4=S0[5],q5=S0[6],q6=S0[0];
  float lvl = xT[b]/S0[0];
  lvlT[b] = lvl;
  for(int t=1;t<300;t++){
    float xt = xT[t*128+b];
    float s  = q0;
    lvl = a*(xt/s) + (1.0f-a)*lvl;
    float sn = g*(xt/lvl) + (1.0f-g)*s;
    q0=q1;q1=q2;q2=q3;q3=q4;q4=q5;q5=q6;q6=sn;
    lvlT[t*128+b]   = lvl;
    ST[(t+7)*128+b] = sn;
  }
}

// ---- build window_input for the 10 distinct rows: win[(t*10+j)*49 + f] ----
__global__ void k_win(const float* __restrict__ xT, const float* __restrict__ ST,
                      const float* __restrict__ lvlT, const float* __restrict__ cats,
                      const float* __restrict__ mp, float* __restrict__ win){
  int i = blockIdx.x*256 + threadIdx.x;
  if(i >= NM*49) return;
  int f = i % 49;
  int m = i / 49;
  int j = m % 10, t = m / 10;
  float v;
  if(f < 28){
    int c = t + f;
    v = xT[c*128 + j] / ST[c*128 + j] / lvlT[(t+27)*128 + j];
  } else if(f < 48){
    v = cats[j*20 + (f-28)];
  } else {
    v = mp[0];
  }
  win[i] = v;
}

// ---- actual_values (window_output), per real batch row b (f32 out) ----
__global__ void k_wout(const float* __restrict__ xT, const float* __restrict__ ST,
                       const float* __restrict__ lvlT, float* __restrict__ out1){
  int i = blockIdx.x*256 + threadIdx.x;
  if(i >= N_O0) return;
  int o = i % 28;
  int b = (i/28) % 128;
  int t = i/(28*128);
  int c = 28 + t + o;                    // L + t + o  (<= 299)
  out1[i] = xT[c*128+b] / ST[c*128+b] / lvlT[(27+t)*128+b];
}

// ---- batched xz = X @ WihT + b : block = 8 rows x 1024 gates, 256 threads ----
__global__ __launch_bounds__(256) void k_gemm(const float* __restrict__ X,
                                              const float* __restrict__ WT,   // [F][1024] f32
                                              const float* __restrict__ bias, // [1024] f32
                                              float* __restrict__ Z, int F){
  __shared__ float Xs[8][256];
  const int tid = threadIdx.x;
  const int m0 = blockIdx.x*8;
  for(int p=0;p<8;p++){
    int m = m0+p;
    for(int f=tid; f<F; f+=256)
      Xs[p][f] = (m < NM) ? X[m*F+f] : 0.0f;
  }
  __syncthreads();
  float acc0[8], acc1[8], acc2[8], acc3[8];
  {
    float b0 = bias[tid];
    float b1 = bias[tid+256];
    float b2 = bias[tid+512];
    float b3 = bias[tid+768];
    #pragma unroll
    for(int p=0;p<8;p++){ acc0[p]=b0; acc1[p]=b1; acc2[p]=b2; acc3[p]=b3; }
  }
  #pragma unroll 4
  for(int f=0; f<F; f++){
    float w0 = WT[f*1024 + tid      ];
    float w1 = WT[f*1024 + tid+256  ];
    float w2 = WT[f*1024 + tid+512  ];
    float w3 = WT[f*1024 + tid+768  ];
    #pragma unroll
    for(int p=0;p<8;p++){
      float xv = Xs[p][f];
      acc0[p] += w0*xv; acc1[p] += w1*xv; acc2[p] += w2*xv; acc3[p] += w3*xv;
    }
  }
  for(int p=0;p<8;p++){
    int m = m0+p;
    if(m < NM){
      float* zb = Z + m*1024 + tid;
      zb[0]=acc0[p]; zb[256]=acc1[p]; zb[512]=acc2[p]; zb[768]=acc3[p];
    }
  }
}

// ---- LSTM scan: one WG (512 thr) per (dilation-phase r, row j) chain ----
// bf16-packed WhhT stream: halves the per-step L2 traffic vs f32 (the
// measured bound in R3: 1MB/step @ ~56 B/cyc/CU = 7.8 us/step).
// phase1: thread (kg,js): gates kg*8..kg*8+7, K-slice js*64..js*64+63 -> zp
// combine: 256 threads: sum partials + xz, gate math, h/c update
__global__ __launch_bounds__(512) void k_scan(const float* __restrict__ Z,
                                              const u16* __restrict__ WT,   // [256][1024] bf16 (WhhT [k][row])
                                              float* __restrict__ Y,
                                              const float* __restrict__ RES,
                                              int d){
  __shared__ float h_lds[256];
  __shared__ float c_lds[256];
  __shared__ float zp[4][1024];
  const int tid = threadIdx.x;
  const int chain = blockIdx.x;
  const int j = chain % 10;
  const int r = chain / 10;
  const int ns = (273 - r + d - 1)/d;     // skip trailing padded steps
  const int kg = tid & 127;
  const int js = tid >> 7;
  const u16* Wb = WT + js*64*1024 + kg*8;
  if(tid < 256){ h_lds[tid] = 0.0f; c_lds[tid] = 0.0f; }
  __syncthreads();
  int t = r;
  for(int s=0; s<ns; s++, t+=d){
    float a0=0,a1=0,a2=0,a3=0,a4=0,a5=0,a6=0,a7=0;
    const float* hp = h_lds + js*64;
    #pragma unroll 8
    for(int jj=0;jj<64;jj++){
      float hv = hp[jj];
      uint4 w = *(const uint4*)(Wb + jj*1024);   // 8 bf16 = 16B
      a0 += __uint_as_float(w.x<<16)           * hv;
      a1 += __uint_as_float(w.x & 0xffff0000u) * hv;
      a2 += __uint_as_float(w.y<<16)           * hv;
      a3 += __uint_as_float(w.y & 0xffff0000u) * hv;
      a4 += __uint_as_float(w.z<<16)           * hv;
      a5 += __uint_as_float(w.z & 0xffff0000u) * hv;
      a6 += __uint_as_float(w.w<<16)           * hv;
      a7 += __uint_as_float(w.w & 0xffff0000u) * hv;
    }
    float4* zr = (float4*)&zp[js][kg*8];
    zr[0] = make_float4(a0,a1,a2,a3);
    zr[1] = make_float4(a4,a5,a6,a7);
    __syncthreads();
    if(tid < 256){
      const int u = tid;
      const float* zb = Z + (size_t)(t*10 + j)*1024;
      float zi = zb[u]     + zp[0][u]     + zp[1][u]     + zp[2][u]     + zp[3][u];
      float zf = zb[u+256] + zp[0][u+256] + zp[1][u+256] + zp[2][u+256] + zp[3][u+256];
      float zg = zb[u+512] + zp[0][u+512] + zp[1][u+512] + zp[2][u+512] + zp[3][u+512];
      float zo = zb[u+768] + zp[0][u+768] + zp[1][u+768] + zp[2][u+768] + zp[3][u+768];
      float c  = sigf(zf)*c_lds[u] + sigf(zi)*tanh_(zg);
      float h  = sigf(zo)*tanh_(c);
      c_lds[u] = c; h_lds[u] = h;
      float o = h;
      if(RES) o += RES[(size_t)(t*10+j)*256 + u];
      Y[(size_t)(t*10+j)*256 + u] = o;
    }
    __syncthreads();
  }
}

// ---- head: h = tanh(y4 @ linW.T + lb); rnn = h @ scW.T + sb ----
__global__ __launch_bounds__(256) void k_head(const float* __restrict__ Y4,
    const float* __restrict__ LWT,  // [256][256] f32 (linWT: [f][u])
    const float* __restrict__ lb,
    const float* __restrict__ SWT,  // [256][28] f32  (scoreT: [f][o])
    const float* __restrict__ sb,
    float* __restrict__ R){
  __shared__ float v [8][256];
  __shared__ float h2[8][256];
  const int tid = threadIdx.x;
  const int m0 = blockIdx.x*8;
  for(int p=0;p<8;p++){
    int m = m0+p;
    v[p][tid] = (m<NM) ? Y4[m*256+tid] : 0.0f;
  }
  __syncthreads();
  float acc[8];
  float bz = lb[tid];
  #pragma unroll
  for(int p=0;p<8;p++) acc[p]=bz;
  #pragma unroll 4
  for(int f=0; f<256; f++){
    float w = LWT[f*256+tid];
    #pragma unroll
    for(int p=0;p<8;p++) acc[p] += w * v[p][f];
  }
  #pragma unroll
  for(int p=0;p<8;p++) h2[p][tid] = tanh_(acc[p]);
  __syncthreads();
  if(tid < 224){
    int o = tid % 28, p = tid / 28;
    int m = m0 + p;
    if(m < NM){
      float a = sb[o];
      for(int f=0; f<256; f++) a += SWT[f*28+o] * h2[p][f];
      R[m*28+o] = a;
    }
  }
}

// ---- final outputs (f32) ----
// S_ext = concat(S_full[0:307], S_full[300:307]); S_ext[-28:][o] =
//   S_full[286+o] (o<21) else S_full[279+o]
__global__ void k_out(const float* __restrict__ R, const float* __restrict__ ST,
                      const float* __restrict__ lvlT, const float* __restrict__ val,
                      float* __restrict__ out){
  int i = blockIdx.x*256 + threadIdx.x;
  float* o0 = out;                 // prediction_values (245,128,28)
  float* o2 = out + 1756160;       // holdout_prediction (128,28)
  float* o3 = out + 1759744;       // rnn_out (273,128,28)
  float* o4 = out + 2738176;       // hav (128,28)
  float* o5 = out + 2741760;       // hav_norm (128,28)
  if(i < N_O3){
    int o = i % 28;
    int b = (i/28) % 128;
    int t = i/(28*128);
    float vv = R[(t*10 + (b%10))*28 + o];
    o3[i] = vv;
    if(i < N_O0) o0[i] = vv;       // rnn_out[:-OUT], same linear layout
  }
  if(i < 128*28){
    int b = i/28, o = i%28;
    int col = (o < 21) ? (286+o) : (279+o);
    float Sm = ST[col*128 + b];
    float lv = lvlT[299*128 + b];
    float hv = R[(2720 + (b%10))*28 + o] * Sm * lv;
    o2[i] = (hv > 0.0f) ? hv : 0.0f;
    o4[i] = val[i];
    o5[i] = val[i] / Sm / lv;
  }
}

extern "C" void kernel_launch(void* const* d_in, const int* in_sizes, int n_in,
                              void* d_out, int out_size, void* d_ws, size_t ws_size,
                              hipStream_t stream){
  (void)in_sizes; (void)n_in; (void)out_size; (void)ws_size;
  const float* x     = (const float*)d_in[0];
  const float* val   = (const float*)d_in[1];
  const float* alpha = (const float*)d_in[2];
  const float* gamma = (const float*)d_in[3];
  const float* iseas = (const float*)d_in[4];
  const float* cats  = (const float*)d_in[5];
  const float* mp    = (const float*)d_in[6];
  const float* Wih[4]  = {(const float*)d_in[7],  (const float*)d_in[10], (const float*)d_in[13], (const float*)d_in[16]};
  const float* Whh[4]  = {(const float*)d_in[8],  (const float*)d_in[11], (const float*)d_in[14], (const float*)d_in[17]};
  const float* bias[4] = {(const float*)d_in[9],  (const float*)d_in[12], (const float*)d_in[15], (const float*)d_in[18]};
  const float* linW  = (const float*)d_in[19];
  const float* linb  = (const float*)d_in[20];
  const float* scW   = (const float*)d_in[21];
  const float* scb   = (const float*)d_in[22];

  // ---- workspace layout: f32 region, then 16B-aligned bf16 Whh region ----
  float* Fw   = (float*)d_ws;
  float* ST   = Fw;                 // 39296
  float* lvlT = ST   + 39296;       // 38400
  float* xT   = lvlT + 38400;       // 38400
  float* win  = xT   + 38400;       // 133776
  float* xz   = win  + 133776;      // 2795520
  float* yA   = xz   + 2795520;     // 698880  (L1 out / L3 out / L4 out)
  float* yB   = yA   + 698880;      // 698880  (L2 out, residual)
  float* rnn  = yB   + 698880;      // 76448
  float* wihT[4];
  wihT[0] = rnn + 76448;            // 50176
  wihT[1] = wihT[0] + 50176;        // 262144
  wihT[2] = wihT[1] + 262144;
  wihT[3] = wihT[2] + 262144;
  float* linWT = wihT[3] + 262144;  // 65536
  float* scT   = linWT + 65536;     // 7168
  u16*   WB16  = (u16*)(scT + 7168);           // f32 count %4==0 -> 16B aligned
  u16*   whhT[4];
  for(int l=0;l<4;l++) whhT[l] = WB16 + (size_t)l*262144;   // 4 * 512KB bf16

  // ---- weight prep ----
  for(int l=0;l<4;l++)
    k_trb<<<(262144+255)/256, 256, 0, stream>>>(Whh[l], whhT[l], 1024, 256);
  k_trf<<<(1024*49+255)/256, 256, 0, stream>>>(Wih[0], wihT[0], 1024, 49);
  for(int l=1;l<4;l++)
    k_trf<<<(262144+255)/256, 256, 0, stream>>>(Wih[l], wihT[l], 1024, 256);
  k_trf<<<(65536+255)/256, 256, 0, stream>>>(linW, linWT, 256, 256);
  k_trf<<<(7168+255)/256, 256, 0, stream>>>(scW, scT, 28, 256);

  // ---- ES scan + windows ----
  k_xT<<<150, 256, 0, stream>>>(x, xT);
  k_es<<<1, 128, 0, stream>>>(xT, alpha, gamma, iseas, ST, lvlT);
  k_win<<<(NM*49+255)/256, 256, 0, stream>>>(xT, ST, lvlT, cats, mp, win);
  k_wout<<<N_O0/256, 256, 0, stream>>>(xT, ST, lvlT, (float*)d_out + 878080);

  // ---- 4 LSTM layers: batched Wih GEMM + bf16-stream scan ----
  const int    dlt[4]    = {1, 2, 2, 6};
  const int    chains[4] = {10, 20, 20, 60};
  const float* Xin[4]    = {win, yA, yB, yA};
  float*       Yout[4]   = {yA, yB, yA, yA};
  const int    Fdim[4]   = {49, 256, 256, 256};
  for(int l=0;l<4;l++){
    k_gemm<<<(NM+7)/8, 256, 0, stream>>>(Xin[l], wihT[l], bias[l], xz, Fdim[l]);
    k_scan<<<chains[l], 512, 0, stream>>>(xz, whhT[l], Yout[l],
                                          (l==3) ? yB : (const float*)nullptr, dlt[l]);
  }

  // ---- head + outputs ----
  k_head<<<(NM+7)/8, 256, 0, stream>>>(yA, linWT, linb, scT, scb, rnn);
  k_out<<<N_O3/256, 256, 0, stream>>>(rnn, ST, lvlT, val, (float*)d_out);
}